// Round 14
// baseline (163.806 us; speedup 1.0000x reference)
//
#include <hip/hip_runtime.h>
#include <math.h>

constexpr int N_LOC     = 100000;
constexpr int D_IN      = 128;
constexpr int N_ROUTES  = 8192;
constexpr int ROUTE_LEN = 100;
constexpr int D_OUT     = 256;
constexpr float LN_EPS  = 1e-5f;

constexpr int NRANGE   = 8;                      // location ranges == # XCDs
constexpr int RSIZE    = N_LOC / NRANGE;         // 12500 rows -> 3.2 MB fp16 slice
constexpr int RPB      = 4;                      // routes per block (1 per wave)
constexpr int NTHREADS = 256;
constexpr size_t EMB_ELEMS  = (size_t)N_LOC * D_IN;             // 12.8e6
constexpr size_t F16_BYTES  = EMB_ELEMS * 2;                    // 25.6 MB
constexpr size_t PART_U32S  = (size_t)NRANGE * N_ROUTES * (D_IN / 2);
constexpr size_t PART_BYTES = PART_U32S * 4;                    // 16.8 MB

typedef __fp16 f16x2 __attribute__((ext_vector_type(2)));       // matches cvt_pkrtz return

__device__ inline unsigned pk_max_f16(unsigned a, unsigned b) {
    unsigned d;
    asm("v_pk_max_f16 %0, %1, %2" : "=v"(d) : "v"(a), "v"(b));
    return d;
}

// ---- pass 0: fp32 table -> packed-fp16 table in d_ws (streams ~77 MB) ----
__global__ __launch_bounds__(256, 8)
void convert_f16_kernel(const float* __restrict__ emb, unsigned* __restrict__ emb16) {
    size_t i = ((size_t)blockIdx.x * blockDim.x + threadIdx.x) * 4;   // elems
    const size_t stride = (size_t)gridDim.x * blockDim.x * 4;
    for (; i < EMB_ELEMS; i += stride) {
        const float4 v = *reinterpret_cast<const float4*>(emb + i);
        const f16x2 a = __builtin_amdgcn_cvt_pkrtz(v.x, v.y);
        const f16x2 b = __builtin_amdgcn_cvt_pkrtz(v.z, v.w);
        uint2 u;
        u.x = __builtin_bit_cast(unsigned, a);
        u.y = __builtin_bit_cast(unsigned, b);
        *reinterpret_cast<uint2*>(emb16 + i / 2) = u;
    }
}

// ---- pass A: per-(route, location-range) partial max-pool ----
// range = blockIdx & 7 -> default round-robin dispatch pins range slice in one XCD L2.
__global__ __launch_bounds__(NTHREADS, 8)
void pass_a_kernel(const unsigned* __restrict__ emb16,   // [N_LOC][64] u32 (fp16x2)
                   const int*      __restrict__ idx,     // [N_ROUTES][ROUTE_LEN]
                   unsigned*       __restrict__ part)    // [NRANGE][N_ROUTES][64] u32
{
    __shared__ int s_idx[RPB * ROUTE_LEN];

    const int tid    = threadIdx.x;
    const int range  = blockIdx.x & (NRANGE - 1);
    const int rgrp   = blockIdx.x >> 3;
    const int route0 = rgrp * RPB;

    for (int i = tid; i < RPB * ROUTE_LEN; i += NTHREADS)
        s_idx[i] = idx[(size_t)route0 * ROUTE_LEN + i];
    __syncthreads();

    const int w    = tid >> 6;     // wave = route
    const int lane = tid & 63;     // lane owns dims 2*lane, 2*lane+1
    const int* gi  = &s_idx[w * ROUTE_LEN];
    const int  lo  = range * RSIZE;

    // build in-range masks for indices [0..63] and [64..99]
    const int i0 = gi[lane];
    const int i1 = (lane < ROUTE_LEN - 64) ? gi[64 + lane] : -1;
    unsigned long long m0 = __ballot((unsigned)(i0 - lo) < (unsigned)RSIZE);
    unsigned long long m1 = __ballot(i1 >= 0 && (unsigned)(i1 - lo) < (unsigned)RSIZE);

    unsigned acc0 = 0xFC00FC00u, acc1 = 0xFC00FC00u;   // packed -inf
    while (m0 | m1) {                                  // wave-uniform; 2-deep MLP
        if (m0) {
            const int l = __ffsll((unsigned long long)m0) - 1; m0 &= m0 - 1;
            const unsigned v = emb16[(size_t)gi[l] * (D_IN / 2) + lane];
            acc0 = pk_max_f16(acc0, v);
        }
        if (m1) {
            const int l = __ffsll((unsigned long long)m1) - 1; m1 &= m1 - 1;
            const unsigned v = emb16[(size_t)gi[64 + l] * (D_IN / 2) + lane];
            acc1 = pk_max_f16(acc1, v);
        }
    }
    const unsigned acc = pk_max_f16(acc0, acc1);
    __builtin_nontemporal_store(
        acc, &part[((size_t)range * N_ROUTES + route0 + w) * (D_IN / 2) + lane]);
}

// ---- pass B: reduce partials -> pooled, then GEMM + LN + ReLU (R8-proven) ----
__global__ __launch_bounds__(NTHREADS, 8)
void pass_b_kernel(const unsigned* __restrict__ part,    // [NRANGE][N_ROUTES][64]
                   const float*    __restrict__ W,
                   const float*    __restrict__ bias,
                   const float*    __restrict__ gamma,
                   const float*    __restrict__ beta,
                   float*          __restrict__ out)
{
    __shared__ float s_pooled[RPB][D_IN];
    __shared__ float s_sum[4][RPB];
    __shared__ float s_ssq[4][RPB];

    const int tid    = threadIdx.x;
    const int route0 = blockIdx.x * RPB;
    const int w      = tid >> 6;
    const int lane   = tid & 63;

    {
        const int route = route0 + w;
        unsigned acc = 0xFC00FC00u;
        #pragma unroll
        for (int k = 0; k < NRANGE; ++k)
            acc = pk_max_f16(acc, part[((size_t)k * N_ROUTES + route) * (D_IN / 2) + lane]);
        const f16x2 h = __builtin_bit_cast(f16x2, acc);
        s_pooled[w][2 * lane]     = (float)h.x;
        s_pooled[w][2 * lane + 1] = (float)h.y;
    }
    __syncthreads();

    // GEMM + bias (thread = output column; W read once per block)
    float h[RPB];
    {
        const float bo = bias[tid];
        #pragma unroll
        for (int r = 0; r < RPB; ++r) h[r] = bo;

        #pragma unroll 8
        for (int k = 0; k < D_IN; k += 4) {
            const float wk0 = W[(size_t)(k + 0) * D_OUT + tid];
            const float wk1 = W[(size_t)(k + 1) * D_OUT + tid];
            const float wk2 = W[(size_t)(k + 2) * D_OUT + tid];
            const float wk3 = W[(size_t)(k + 3) * D_OUT + tid];
            #pragma unroll
            for (int r = 0; r < RPB; ++r) {
                const float4 p = *reinterpret_cast<const float4*>(&s_pooled[r][k]);
                h[r] = fmaf(p.x, wk0, h[r]);
                h[r] = fmaf(p.y, wk1, h[r]);
                h[r] = fmaf(p.z, wk2, h[r]);
                h[r] = fmaf(p.w, wk3, h[r]);
            }
        }
    }

    // LayerNorm (E[x^2]-mu^2) + ReLU
    float s[RPB], ss[RPB];
    #pragma unroll
    for (int r = 0; r < RPB; ++r) { s[r] = h[r]; ss[r] = h[r] * h[r]; }

    #pragma unroll
    for (int off = 32; off > 0; off >>= 1) {
        #pragma unroll
        for (int r = 0; r < RPB; ++r) {
            s[r]  += __shfl_down(s[r],  off);
            ss[r] += __shfl_down(ss[r], off);
        }
    }
    if (lane == 0) {
        #pragma unroll
        for (int r = 0; r < RPB; ++r) { s_sum[w][r] = s[r]; s_ssq[w][r] = ss[r]; }
    }
    __syncthreads();

    const float gm = gamma[tid];
    const float bt = beta[tid];
    #pragma unroll
    for (int r = 0; r < RPB; ++r) {
        const float tot = s_sum[0][r] + s_sum[1][r] + s_sum[2][r] + s_sum[3][r];
        const float tsq = s_ssq[0][r] + s_ssq[1][r] + s_ssq[2][r] + s_ssq[3][r];
        const float mu  = tot * (1.0f / D_OUT);
        const float var = tsq * (1.0f / D_OUT) - mu * mu;
        const float inv = rsqrtf(var + LN_EPS);
        const float y   = fmaxf((h[r] - mu) * inv * gm + bt, 0.0f);
        __builtin_nontemporal_store(y, &out[(size_t)(route0 + r) * D_OUT + tid]);
    }
}

// ---- fallback: R8-proven single fused kernel (fp16 table, no partitioning) ----
template<bool F16>
__global__ __launch_bounds__(NTHREADS, 8)
void routes_encoder_kernel(const float*    __restrict__ emb,
                           const unsigned* __restrict__ emb16,
                           const int*      __restrict__ idx,
                           const float*    __restrict__ W,
                           const float*    __restrict__ bias,
                           const float*    __restrict__ gamma,
                           const float*    __restrict__ beta,
                           float*          __restrict__ out)
{
    __shared__ int   s_idx[RPB * ROUTE_LEN];
    __shared__ float s_pooled[RPB][D_IN];
    __shared__ float s_sum[4][RPB];
    __shared__ float s_ssq[4][RPB];

    const int tid    = threadIdx.x;
    const int route0 = blockIdx.x * RPB;

    for (int i = tid; i < RPB * ROUTE_LEN; i += NTHREADS)
        s_idx[i] = idx[(size_t)route0 * ROUTE_LEN + i];
    __syncthreads();

    const int w    = tid >> 6;
    const int lane = tid & 63;

    if constexpr (F16) {
        const int q  = lane >> 4;
        const int dc = (lane & 15) * 8;
        const int* gi = &s_idx[w * ROUTE_LEN];
        unsigned m0 = 0xFC00FC00u, m1 = m0, m2 = m0, m3 = m0;
        #pragma unroll 5
        for (int t = 0; t < ROUTE_LEN / 4; ++t) {
            const int row = gi[4 * t + q];
            const uint4 v = *reinterpret_cast<const uint4*>(
                emb16 + ((size_t)row * D_IN + dc) / 2);
            m0 = pk_max_f16(m0, v.x);
            m1 = pk_max_f16(m1, v.y);
            m2 = pk_max_f16(m2, v.z);
            m3 = pk_max_f16(m3, v.w);
        }
        #pragma unroll
        for (int off = 32; off >= 16; off >>= 1) {
            m0 = pk_max_f16(m0, (unsigned)__shfl_down((int)m0, off));
            m1 = pk_max_f16(m1, (unsigned)__shfl_down((int)m1, off));
            m2 = pk_max_f16(m2, (unsigned)__shfl_down((int)m2, off));
            m3 = pk_max_f16(m3, (unsigned)__shfl_down((int)m3, off));
        }
        if (lane < 16) {
            const f16x2 h0 = __builtin_bit_cast(f16x2, m0);
            const f16x2 h1 = __builtin_bit_cast(f16x2, m1);
            const f16x2 h2 = __builtin_bit_cast(f16x2, m2);
            const f16x2 h3 = __builtin_bit_cast(f16x2, m3);
            *reinterpret_cast<float4*>(&s_pooled[w][dc]) =
                make_float4((float)h0.x, (float)h0.y, (float)h1.x, (float)h1.y);
            *reinterpret_cast<float4*>(&s_pooled[w][dc + 4]) =
                make_float4((float)h2.x, (float)h2.y, (float)h3.x, (float)h3.y);
        }
    } else {
        const int* gi = &s_idx[w * ROUTE_LEN];
        float2 m = make_float2(-INFINITY, -INFINITY);
        #pragma unroll 10
        for (int l = 0; l < ROUTE_LEN; ++l) {
            const float2 v = *reinterpret_cast<const float2*>(
                emb + (size_t)gi[l] * D_IN + lane * 2);
            m.x = fmaxf(m.x, v.x);
            m.y = fmaxf(m.y, v.y);
        }
        *reinterpret_cast<float2*>(&s_pooled[w][lane * 2]) = m;
    }
    __syncthreads();

    float h[RPB];
    {
        const float bo = bias[tid];
        #pragma unroll
        for (int r = 0; r < RPB; ++r) h[r] = bo;
        #pragma unroll 8
        for (int k = 0; k < D_IN; k += 4) {
            const float wk0 = W[(size_t)(k + 0) * D_OUT + tid];
            const float wk1 = W[(size_t)(k + 1) * D_OUT + tid];
            const float wk2 = W[(size_t)(k + 2) * D_OUT + tid];
            const float wk3 = W[(size_t)(k + 3) * D_OUT + tid];
            #pragma unroll
            for (int r = 0; r < RPB; ++r) {
                const float4 p = *reinterpret_cast<const float4*>(&s_pooled[r][k]);
                h[r] = fmaf(p.x, wk0, h[r]);
                h[r] = fmaf(p.y, wk1, h[r]);
                h[r] = fmaf(p.z, wk2, h[r]);
                h[r] = fmaf(p.w, wk3, h[r]);
            }
        }
    }

    float s[RPB], ss[RPB];
    #pragma unroll
    for (int r = 0; r < RPB; ++r) { s[r] = h[r]; ss[r] = h[r] * h[r]; }
    #pragma unroll
    for (int off = 32; off > 0; off >>= 1) {
        #pragma unroll
        for (int r = 0; r < RPB; ++r) {
            s[r]  += __shfl_down(s[r],  off);
            ss[r] += __shfl_down(ss[r], off);
        }
    }
    if (lane == 0) {
        #pragma unroll
        for (int r = 0; r < RPB; ++r) { s_sum[w][r] = s[r]; s_ssq[w][r] = ss[r]; }
    }
    __syncthreads();

    const float gm = gamma[tid];
    const float bt = beta[tid];
    #pragma unroll
    for (int r = 0; r < RPB; ++r) {
        const float tot = s_sum[0][r] + s_sum[1][r] + s_sum[2][r] + s_sum[3][r];
        const float tsq = s_ssq[0][r] + s_ssq[1][r] + s_ssq[2][r] + s_ssq[3][r];
        const float mu  = tot * (1.0f / D_OUT);
        const float var = tsq * (1.0f / D_OUT) - mu * mu;
        const float inv = rsqrtf(var + LN_EPS);
        const float y   = fmaxf((h[r] - mu) * inv * gm + bt, 0.0f);
        __builtin_nontemporal_store(y, &out[(size_t)(route0 + r) * D_OUT + tid]);
    }
}

extern "C" void kernel_launch(void* const* d_in, const int* in_sizes, int n_in,
                              void* d_out, int out_size, void* d_ws, size_t ws_size,
                              hipStream_t stream) {
    const float* emb   = (const float*)d_in[0];
    const int*   idx   = (const int*)  d_in[1];
    const float* W     = (const float*)d_in[2];
    const float* bias  = (const float*)d_in[3];
    const float* gamma = (const float*)d_in[4];
    const float* beta  = (const float*)d_in[5];
    float* out = (float*)d_out;

    if (ws_size >= F16_BYTES + PART_BYTES) {
        unsigned* emb16 = (unsigned*)d_ws;
        unsigned* part  = (unsigned*)((char*)d_ws + F16_BYTES);
        convert_f16_kernel<<<dim3(2048), dim3(256), 0, stream>>>(emb, emb16);
        pass_a_kernel<<<dim3((N_ROUTES / RPB) * NRANGE), dim3(NTHREADS), 0, stream>>>(
            emb16, idx, part);
        pass_b_kernel<<<dim3(N_ROUTES / RPB), dim3(NTHREADS), 0, stream>>>(
            part, W, bias, gamma, beta, out);
    } else if (ws_size >= F16_BYTES) {
        unsigned* emb16 = (unsigned*)d_ws;
        convert_f16_kernel<<<dim3(2048), dim3(256), 0, stream>>>(emb, emb16);
        routes_encoder_kernel<true><<<dim3(N_ROUTES / RPB), dim3(NTHREADS), 0, stream>>>(
            emb, emb16, idx, W, bias, gamma, beta, out);
    } else {
        routes_encoder_kernel<false><<<dim3(N_ROUTES / RPB), dim3(NTHREADS), 0, stream>>>(
            emb, nullptr, idx, W, bias, gamma, beta, out);
    }
}

// Round 16
// 142.395 us; speedup vs baseline: 1.1504x; 1.1504x over previous
//
#include <hip/hip_runtime.h>
#include <math.h>

constexpr int N_LOC     = 100000;
constexpr int D_IN      = 128;
constexpr int N_ROUTES  = 8192;
constexpr int ROUTE_LEN = 100;
constexpr int D_OUT     = 256;
constexpr float LN_EPS  = 1e-5f;

constexpr int NRANGE   = 8;                      // location ranges == # XCDs
constexpr int RSIZE    = N_LOC / NRANGE;         // 12500 rows -> 3.2 MB fp16 slice
constexpr int RPB      = 4;                      // routes per block (1 per wave)
constexpr int NTHREADS = 256;
constexpr size_t EMB_ELEMS  = (size_t)N_LOC * D_IN;             // 12.8e6
constexpr size_t F16_BYTES  = EMB_ELEMS * 2;                    // 25.6 MB
constexpr size_t PART_U32S  = (size_t)NRANGE * N_ROUTES * (D_IN / 2);
constexpr size_t PART_BYTES = PART_U32S * 4;                    // 16.8 MB

typedef __fp16 f16x2 __attribute__((ext_vector_type(2)));       // matches cvt_pkrtz return

__device__ inline unsigned pk_max_f16(unsigned a, unsigned b) {
    unsigned d;
    asm("v_pk_max_f16 %0, %1, %2" : "=v"(d) : "v"(a), "v"(b));
    return d;
}

// ---- pass 0: fp32 table -> packed-fp16 table in d_ws (streams ~77 MB) ----
__global__ __launch_bounds__(256, 8)
void convert_f16_kernel(const float* __restrict__ emb, unsigned* __restrict__ emb16) {
    size_t i = ((size_t)blockIdx.x * blockDim.x + threadIdx.x) * 4;   // elems
    const size_t stride = (size_t)gridDim.x * blockDim.x * 4;
    for (; i < EMB_ELEMS; i += stride) {
        const float4 v = *reinterpret_cast<const float4*>(emb + i);
        const f16x2 a = __builtin_amdgcn_cvt_pkrtz(v.x, v.y);
        const f16x2 b = __builtin_amdgcn_cvt_pkrtz(v.z, v.w);
        uint2 u;
        u.x = __builtin_bit_cast(unsigned, a);
        u.y = __builtin_bit_cast(unsigned, b);
        *reinterpret_cast<uint2*>(emb16 + i / 2) = u;
    }
}

// ---- pass A v2: compact in-range indices per wave, then 8-deep batched gather ----
// range = blockIdx & 7 -> default round-robin dispatch pins range slice in one XCD L2.
__global__ __launch_bounds__(NTHREADS, 8)
void pass_a_kernel(const unsigned* __restrict__ emb16,   // [N_LOC][64] u32 (fp16x2)
                   const int*      __restrict__ idx,     // [N_ROUTES][ROUTE_LEN]
                   unsigned*       __restrict__ part)    // [NRANGE][N_ROUTES][64] u32
{
    __shared__ int s_idx[RPB * ROUTE_LEN];
    __shared__ int s_comp[RPB][112];                     // compacted + pad (<=104, 8-aligned)

    const int tid    = threadIdx.x;
    const int range  = blockIdx.x & (NRANGE - 1);
    const int rgrp   = blockIdx.x >> 3;
    const int route0 = rgrp * RPB;

    for (int i = tid; i < RPB * ROUTE_LEN; i += NTHREADS)
        s_idx[i] = idx[(size_t)route0 * ROUTE_LEN + i];
    __syncthreads();

    const int w    = tid >> 6;     // wave = route
    const int lane = tid & 63;     // lane owns dims 2*lane, 2*lane+1
    const int* gi  = &s_idx[w * ROUTE_LEN];
    const int  lo  = range * RSIZE;

    // ---- wave-level compaction of in-range indices (ballot + popcount positions) ----
    const int  i0  = gi[lane];
    const bool in0 = (unsigned)(i0 - lo) < (unsigned)RSIZE;
    const int  i1  = (lane < ROUTE_LEN - 64) ? gi[64 + lane] : 0;
    const bool in1 = (lane < ROUTE_LEN - 64) && ((unsigned)(i1 - lo) < (unsigned)RSIZE);
    const unsigned long long m0 = __ballot(in0);
    const unsigned long long m1 = __ballot(in1);
    const int c0 = __popcll(m0);
    const int n  = c0 + __popcll(m1);

    unsigned acc0 = 0xFC00FC00u, acc1 = acc0, acc2 = acc0, acc3 = acc0;  // packed -inf

    if (n > 0) {
        const unsigned long long below = (1ull << lane) - 1;
        if (in0) s_comp[w][__popcll(m0 & below)]      = i0;
        if (in1) s_comp[w][c0 + __popcll(m1 & below)] = i1;

        // pad to multiple of 8 with a duplicate in-range index (max is idempotent)
        const int src    = (m0 ? __ffsll(m0) : __ffsll(m1)) - 1;
        const int padIdx = m0 ? __shfl(i0, src) : __shfl(i1, src);
        const int nPad   = (n + 7) & ~7;
        if (lane < nPad - n) s_comp[w][n + lane] = padIdx;

        // ---- batched gather: 8 independent row loads in flight per iteration ----
        for (int i = 0; i < nPad; i += 8) {
            int rows[8];
            #pragma unroll
            for (int k = 0; k < 8; ++k) rows[k] = s_comp[w][i + k];   // broadcast LDS reads
            unsigned v[8];
            #pragma unroll
            for (int k = 0; k < 8; ++k)
                v[k] = emb16[(size_t)rows[k] * (D_IN / 2) + lane];
            acc0 = pk_max_f16(acc0, v[0]);
            acc1 = pk_max_f16(acc1, v[1]);
            acc2 = pk_max_f16(acc2, v[2]);
            acc3 = pk_max_f16(acc3, v[3]);
            acc0 = pk_max_f16(acc0, v[4]);
            acc1 = pk_max_f16(acc1, v[5]);
            acc2 = pk_max_f16(acc2, v[6]);
            acc3 = pk_max_f16(acc3, v[7]);
        }
    }
    const unsigned acc = pk_max_f16(pk_max_f16(acc0, acc1), pk_max_f16(acc2, acc3));
    __builtin_nontemporal_store(
        acc, &part[((size_t)range * N_ROUTES + route0 + w) * (D_IN / 2) + lane]);
}

// ---- pass B: reduce partials -> pooled, then GEMM + LN + ReLU (R8-proven) ----
__global__ __launch_bounds__(NTHREADS, 8)
void pass_b_kernel(const unsigned* __restrict__ part,    // [NRANGE][N_ROUTES][64]
                   const float*    __restrict__ W,
                   const float*    __restrict__ bias,
                   const float*    __restrict__ gamma,
                   const float*    __restrict__ beta,
                   float*          __restrict__ out)
{
    __shared__ float s_pooled[RPB][D_IN];
    __shared__ float s_sum[4][RPB];
    __shared__ float s_ssq[4][RPB];

    const int tid    = threadIdx.x;
    const int route0 = blockIdx.x * RPB;
    const int w      = tid >> 6;
    const int lane   = tid & 63;

    {
        const int route = route0 + w;
        unsigned acc = 0xFC00FC00u;
        #pragma unroll
        for (int k = 0; k < NRANGE; ++k)
            acc = pk_max_f16(acc, part[((size_t)k * N_ROUTES + route) * (D_IN / 2) + lane]);
        const f16x2 h = __builtin_bit_cast(f16x2, acc);
        s_pooled[w][2 * lane]     = (float)h.x;
        s_pooled[w][2 * lane + 1] = (float)h.y;
    }
    __syncthreads();

    // GEMM + bias (thread = output column; W read once per block)
    float h[RPB];
    {
        const float bo = bias[tid];
        #pragma unroll
        for (int r = 0; r < RPB; ++r) h[r] = bo;

        #pragma unroll 8
        for (int k = 0; k < D_IN; k += 4) {
            const float wk0 = W[(size_t)(k + 0) * D_OUT + tid];
            const float wk1 = W[(size_t)(k + 1) * D_OUT + tid];
            const float wk2 = W[(size_t)(k + 2) * D_OUT + tid];
            const float wk3 = W[(size_t)(k + 3) * D_OUT + tid];
            #pragma unroll
            for (int r = 0; r < RPB; ++r) {
                const float4 p = *reinterpret_cast<const float4*>(&s_pooled[r][k]);
                h[r] = fmaf(p.x, wk0, h[r]);
                h[r] = fmaf(p.y, wk1, h[r]);
                h[r] = fmaf(p.z, wk2, h[r]);
                h[r] = fmaf(p.w, wk3, h[r]);
            }
        }
    }

    // LayerNorm (E[x^2]-mu^2) + ReLU
    float s[RPB], ss[RPB];
    #pragma unroll
    for (int r = 0; r < RPB; ++r) { s[r] = h[r]; ss[r] = h[r] * h[r]; }

    #pragma unroll
    for (int off = 32; off > 0; off >>= 1) {
        #pragma unroll
        for (int r = 0; r < RPB; ++r) {
            s[r]  += __shfl_down(s[r],  off);
            ss[r] += __shfl_down(ss[r], off);
        }
    }
    if (lane == 0) {
        #pragma unroll
        for (int r = 0; r < RPB; ++r) { s_sum[w][r] = s[r]; s_ssq[w][r] = ss[r]; }
    }
    __syncthreads();

    const float gm = gamma[tid];
    const float bt = beta[tid];
    #pragma unroll
    for (int r = 0; r < RPB; ++r) {
        const float tot = s_sum[0][r] + s_sum[1][r] + s_sum[2][r] + s_sum[3][r];
        const float tsq = s_ssq[0][r] + s_ssq[1][r] + s_ssq[2][r] + s_ssq[3][r];
        const float mu  = tot * (1.0f / D_OUT);
        const float var = tsq * (1.0f / D_OUT) - mu * mu;
        const float inv = rsqrtf(var + LN_EPS);
        const float y   = fmaxf((h[r] - mu) * inv * gm + bt, 0.0f);
        __builtin_nontemporal_store(y, &out[(size_t)(route0 + r) * D_OUT + tid]);
    }
}

// ---- fallback: R8-proven single fused kernel (fp16 table, no partitioning) ----
template<bool F16>
__global__ __launch_bounds__(NTHREADS, 8)
void routes_encoder_kernel(const float*    __restrict__ emb,
                           const unsigned* __restrict__ emb16,
                           const int*      __restrict__ idx,
                           const float*    __restrict__ W,
                           const float*    __restrict__ bias,
                           const float*    __restrict__ gamma,
                           const float*    __restrict__ beta,
                           float*          __restrict__ out)
{
    __shared__ int   s_idx[RPB * ROUTE_LEN];
    __shared__ float s_pooled[RPB][D_IN];
    __shared__ float s_sum[4][RPB];
    __shared__ float s_ssq[4][RPB];

    const int tid    = threadIdx.x;
    const int route0 = blockIdx.x * RPB;

    for (int i = tid; i < RPB * ROUTE_LEN; i += NTHREADS)
        s_idx[i] = idx[(size_t)route0 * ROUTE_LEN + i];
    __syncthreads();

    const int w    = tid >> 6;
    const int lane = tid & 63;

    if constexpr (F16) {
        const int q  = lane >> 4;
        const int dc = (lane & 15) * 8;
        const int* gi = &s_idx[w * ROUTE_LEN];
        unsigned m0 = 0xFC00FC00u, m1 = m0, m2 = m0, m3 = m0;
        #pragma unroll 5
        for (int t = 0; t < ROUTE_LEN / 4; ++t) {
            const int row = gi[4 * t + q];
            const uint4 v = *reinterpret_cast<const uint4*>(
                emb16 + ((size_t)row * D_IN + dc) / 2);
            m0 = pk_max_f16(m0, v.x);
            m1 = pk_max_f16(m1, v.y);
            m2 = pk_max_f16(m2, v.z);
            m3 = pk_max_f16(m3, v.w);
        }
        #pragma unroll
        for (int off = 32; off >= 16; off >>= 1) {
            m0 = pk_max_f16(m0, (unsigned)__shfl_down((int)m0, off));
            m1 = pk_max_f16(m1, (unsigned)__shfl_down((int)m1, off));
            m2 = pk_max_f16(m2, (unsigned)__shfl_down((int)m2, off));
            m3 = pk_max_f16(m3, (unsigned)__shfl_down((int)m3, off));
        }
        if (lane < 16) {
            const f16x2 h0 = __builtin_bit_cast(f16x2, m0);
            const f16x2 h1 = __builtin_bit_cast(f16x2, m1);
            const f16x2 h2 = __builtin_bit_cast(f16x2, m2);
            const f16x2 h3 = __builtin_bit_cast(f16x2, m3);
            *reinterpret_cast<float4*>(&s_pooled[w][dc]) =
                make_float4((float)h0.x, (float)h0.y, (float)h1.x, (float)h1.y);
            *reinterpret_cast<float4*>(&s_pooled[w][dc + 4]) =
                make_float4((float)h2.x, (float)h2.y, (float)h3.x, (float)h3.y);
        }
    } else {
        const int* gi = &s_idx[w * ROUTE_LEN];
        float2 m = make_float2(-INFINITY, -INFINITY);
        #pragma unroll 10
        for (int l = 0; l < ROUTE_LEN; ++l) {
            const float2 v = *reinterpret_cast<const float2*>(
                emb + (size_t)gi[l] * D_IN + lane * 2);
            m.x = fmaxf(m.x, v.x);
            m.y = fmaxf(m.y, v.y);
        }
        *reinterpret_cast<float2*>(&s_pooled[w][lane * 2]) = m;
    }
    __syncthreads();

    float h[RPB];
    {
        const float bo = bias[tid];
        #pragma unroll
        for (int r = 0; r < RPB; ++r) h[r] = bo;
        #pragma unroll 8
        for (int k = 0; k < D_IN; k += 4) {
            const float wk0 = W[(size_t)(k + 0) * D_OUT + tid];
            const float wk1 = W[(size_t)(k + 1) * D_OUT + tid];
            const float wk2 = W[(size_t)(k + 2) * D_OUT + tid];
            const float wk3 = W[(size_t)(k + 3) * D_OUT + tid];
            #pragma unroll
            for (int r = 0; r < RPB; ++r) {
                const float4 p = *reinterpret_cast<const float4*>(&s_pooled[r][k]);
                h[r] = fmaf(p.x, wk0, h[r]);
                h[r] = fmaf(p.y, wk1, h[r]);
                h[r] = fmaf(p.z, wk2, h[r]);
                h[r] = fmaf(p.w, wk3, h[r]);
            }
        }
    }

    float s[RPB], ss[RPB];
    #pragma unroll
    for (int r = 0; r < RPB; ++r) { s[r] = h[r]; ss[r] = h[r] * h[r]; }
    #pragma unroll
    for (int off = 32; off > 0; off >>= 1) {
        #pragma unroll
        for (int r = 0; r < RPB; ++r) {
            s[r]  += __shfl_down(s[r],  off);
            ss[r] += __shfl_down(ss[r], off);
        }
    }
    if (lane == 0) {
        #pragma unroll
        for (int r = 0; r < RPB; ++r) { s_sum[w][r] = s[r]; s_ssq[w][r] = ss[r]; }
    }
    __syncthreads();

    const float gm = gamma[tid];
    const float bt = beta[tid];
    #pragma unroll
    for (int r = 0; r < RPB; ++r) {
        const float tot = s_sum[0][r] + s_sum[1][r] + s_sum[2][r] + s_sum[3][r];
        const float tsq = s_ssq[0][r] + s_ssq[1][r] + s_ssq[2][r] + s_ssq[3][r];
        const float mu  = tot * (1.0f / D_OUT);
        const float var = tsq * (1.0f / D_OUT) - mu * mu;
        const float inv = rsqrtf(var + LN_EPS);
        const float y   = fmaxf((h[r] - mu) * inv * gm + bt, 0.0f);
        __builtin_nontemporal_store(y, &out[(size_t)(route0 + r) * D_OUT + tid]);
    }
}

extern "C" void kernel_launch(void* const* d_in, const int* in_sizes, int n_in,
                              void* d_out, int out_size, void* d_ws, size_t ws_size,
                              hipStream_t stream) {
    const float* emb   = (const float*)d_in[0];
    const int*   idx   = (const int*)  d_in[1];
    const float* W     = (const float*)d_in[2];
    const float* bias  = (const float*)d_in[3];
    const float* gamma = (const float*)d_in[4];
    const float* beta  = (const float*)d_in[5];
    float* out = (float*)d_out;

    if (ws_size >= F16_BYTES + PART_BYTES) {
        unsigned* emb16 = (unsigned*)d_ws;
        unsigned* part  = (unsigned*)((char*)d_ws + F16_BYTES);
        convert_f16_kernel<<<dim3(2048), dim3(256), 0, stream>>>(emb, emb16);
        pass_a_kernel<<<dim3((N_ROUTES / RPB) * NRANGE), dim3(NTHREADS), 0, stream>>>(
            emb16, idx, part);
        pass_b_kernel<<<dim3(N_ROUTES / RPB), dim3(NTHREADS), 0, stream>>>(
            part, W, bias, gamma, beta, out);
    } else if (ws_size >= F16_BYTES) {
        unsigned* emb16 = (unsigned*)d_ws;
        convert_f16_kernel<<<dim3(2048), dim3(256), 0, stream>>>(emb, emb16);
        routes_encoder_kernel<true><<<dim3(N_ROUTES / RPB), dim3(NTHREADS), 0, stream>>>(
            emb, emb16, idx, W, bias, gamma, beta, out);
    } else {
        routes_encoder_kernel<false><<<dim3(N_ROUTES / RPB), dim3(NTHREADS), 0, stream>>>(
            emb, nullptr, idx, W, bias, gamma, beta, out);
    }
}